// Round 8
// baseline (338.523 us; speedup 1.0000x reference)
//
#include <hip/hip_runtime.h>

#define SEQ 2048
#define HID 2048
#define NH 16
#define HD 128
#define N1 6144   // NH * 3 * HD

typedef __attribute__((ext_vector_type(8))) short short8;
typedef __attribute__((ext_vector_type(8))) __bf16 bf16x8;
typedef __attribute__((ext_vector_type(4))) float f32x4;

__device__ __forceinline__ short f2b(float f) {
  unsigned u = __builtin_bit_cast(unsigned, f);
  unsigned r = (u + 0x7FFFu + ((u >> 16) & 1u)) >> 16;
  return (short)(r & 0xFFFFu);
}
__device__ __forceinline__ float b2f(short s) {
  return __builtin_bit_cast(float, (unsigned)((unsigned short)s) << 16);
}

__device__ __forceinline__ f32x4 mfma16(short8 a, short8 b, f32x4 c) {
  return __builtin_amdgcn_mfma_f32_16x16x32_bf16(
      __builtin_bit_cast(bf16x8, a), __builtin_bit_cast(bf16x8, b), c, 0, 0, 0);
}

// async global->LDS, 16B per lane. LDS dest = wave-uniform base + lane*16.
__device__ __forceinline__ void gload16(const short* g, short* l) {
  __builtin_amdgcn_global_load_lds(
      (const __attribute__((address_space(1))) unsigned int*)g,
      (__attribute__((address_space(3))) unsigned int*)l, 16, 0, 0);
}

// ---------------- cast fp32 -> bf16 bits ----------------
__global__ __launch_bounds__(256) void cast_f32_bf16(const float* __restrict__ in,
                                                     short* __restrict__ out, int n) {
  int i = (blockIdx.x * 256 + threadIdx.x) * 8;
  if (i >= n) return;
  float4 a = *reinterpret_cast<const float4*>(in + i);
  float4 b = *reinterpret_cast<const float4*>(in + i + 4);
  short8 o;
  o[0] = f2b(a.x); o[1] = f2b(a.y); o[2] = f2b(a.z); o[3] = f2b(a.w);
  o[4] = f2b(b.x); o[5] = f2b(b.y); o[6] = f2b(b.z); o[7] = f2b(b.w);
  *reinterpret_cast<short8*>(out + i) = o;
}

// ---------------- transpose + cast: in fp32 [R][C] -> out bf16 [C][R] ----------------
__global__ __launch_bounds__(256) void tr_cast(const float* __restrict__ in,
                                               short* __restrict__ out, int R, int C) {
  __shared__ float t[32][33];
  int c0 = blockIdx.x * 32, r0 = blockIdx.y * 32;
  int tx = threadIdx.x, ty = threadIdx.y;  // (32, 8)
#pragma unroll
  for (int i = 0; i < 4; i++) t[ty + i * 8][tx] = in[(r0 + ty + i * 8) * C + c0 + tx];
  __syncthreads();
#pragma unroll
  for (int i = 0; i < 4; i++) out[(c0 + ty + i * 8) * R + r0 + tx] = f2b(t[tx][ty + i * 8]);
}

// ---------------- GEMM (m97 structure, BK=64 as two proven 32-sub-tiles) ----------------
// C(MxN) = A(MxK) * Bt(NxK)^T + bias. 2 barriers per 64-K step (halved vs BK=32).
// BF16OUT=1 -> bf16 output, else fp32.
template <int BF16OUT>
__global__ __launch_bounds__(256) void gemm_bt(const short* __restrict__ A,
                                               const short* __restrict__ Bt,
                                               const float* __restrict__ bias,
                                               void* __restrict__ Cv,
                                               int M, int N, int K) {
  __shared__ __attribute__((aligned(16))) short aT0[128 * 32];
  __shared__ __attribute__((aligned(16))) short aT1[128 * 32];
  __shared__ __attribute__((aligned(16))) short bT0[128 * 32];
  __shared__ __attribute__((aligned(16))) short bT1[128 * 32];
  int tid = threadIdx.x;
  int wave = tid >> 6, lane = tid & 63;
  int lhi = lane >> 4, llo = lane & 15;
  int wr = wave >> 1, wc = wave & 1;
  int m0 = blockIdx.y * 128, n0 = blockIdx.x * 128;
  int lr = lane >> 2, lc = (lane & 3) * 8;  // staging: lane's row-in-chunk / col

  f32x4 acc[4][4];
#pragma unroll
  for (int a = 0; a < 4; a++)
#pragma unroll
    for (int b = 0; b < 4; b++) acc[a][b] = (f32x4){0.f, 0.f, 0.f, 0.f};

  const short* Ab = A + (long)m0 * K;
  const short* Bb = Bt + (long)n0 * K;

#define COMPUTE_KS(AT, BT)                                                   \
  {                                                                          \
    short8 af[4], bf[4];                                                     \
    _Pragma("unroll") for (int mi = 0; mi < 4; mi++)                         \
        af[mi] = *(const short8*)&AT[(wr * 64 + mi * 16 + llo) * 32 + lhi * 8]; \
    _Pragma("unroll") for (int ni = 0; ni < 4; ni++)                         \
        bf[ni] = *(const short8*)&BT[(wc * 64 + ni * 16 + llo) * 32 + lhi * 8]; \
    _Pragma("unroll") for (int mi = 0; mi < 4; mi++)                         \
        _Pragma("unroll") for (int ni = 0; ni < 4; ni++)                     \
            acc[mi][ni] = mfma16(af[mi], bf[ni], acc[mi][ni]);               \
  }

  for (int k0 = 0; k0 < K; k0 += 64) {
#pragma unroll
    for (int it = 0; it < 2; it++) {
      int c = wave * 2 + it;  // chunk 0..7, 16 rows each
      long rowoff = (long)(c * 16 + lr) * K + k0 + lc;
      gload16(Ab + rowoff, &aT0[c * 512]);
      gload16(Ab + rowoff + 32, &aT1[c * 512]);
      gload16(Bb + rowoff, &bT0[c * 512]);
      gload16(Bb + rowoff + 32, &bT1[c * 512]);
    }
    __syncthreads();
    COMPUTE_KS(aT0, bT0);
    COMPUTE_KS(aT1, bT1);
    __syncthreads();
  }
#undef COMPUTE_KS

#pragma unroll
  for (int mi = 0; mi < 4; mi++)
#pragma unroll
    for (int ni = 0; ni < 4; ni++)
#pragma unroll
      for (int r = 0; r < 4; r++) {
        int row = m0 + wr * 64 + mi * 16 + lhi * 4 + r;
        int col = n0 + wc * 64 + ni * 16 + llo;
        float v = acc[mi][ni][r] + bias[col];
        if (BF16OUT)
          ((short*)Cv)[row * (long)N + col] = f2b(v);
        else
          ((float*)Cv)[row * (long)N + col] = v;
      }
}

// ---------------- Fused RoPE(Q,K) + V transpose (proven R4 version) ----------------
// qkv bf16 [s][h*384+e] -> Qb/Kb bf16 [h][s][d] (Q pre-scaled), Vt bf16 [h][d][s]
__global__ __launch_bounds__(256) void rope_v(const short* __restrict__ qkv,
                                              short* __restrict__ Qb,
                                              short* __restrict__ Kb,
                                              short* __restrict__ Vt) {
  __shared__ short t[32][33];
  const float INVNORM = 0.08838834764831845f;  // 1/sqrt(128)
  int d0 = blockIdx.x * 32, s0 = blockIdx.y * 32, h = blockIdx.z;
  int tx = threadIdx.x, ty = threadIdx.y;  // (32, 8)
#pragma unroll
  for (int i = 0; i < 4; i++) {
    int s = s0 + ty + i * 8;
    int base = s * N1 + h * 384;
    t[ty + i * 8][tx] = qkv[base + 256 + d0 + tx];
    float q = b2f(qkv[base + d0 + tx]);
    float k = b2f(qkv[base + 128 + d0 + tx]);
    if (d0 == 0) {
      float qo = __shfl_xor(q, 16);
      float ko = __shfl_xor(k, 16);
      int ii = tx & 15;
      float inv_freq = exp2f(-(float)ii * 0.8304820237218407f);
      float fr = (float)s * inv_freq;
      float c, sn;
      sincosf(fr, &sn, &c);
      float sgn = (tx < 16) ? -1.f : 1.f;
      q = q * c + sgn * qo * sn;
      k = k * c + sgn * ko * sn;
    }
    int o = (h * SEQ + s) * HD + d0 + tx;
    Qb[o] = f2b(q * INVNORM);
    Kb[o] = f2b(k);
  }
  __syncthreads();
#pragma unroll
  for (int i = 0; i < 4; i++)
    Vt[(h * HD + d0 + ty + i * 8) * SEQ + s0 + tx] = t[tx][ty + i * 8];
}

// ---------------- Out-proj GEMM, BM=64, BK=64 two-sub-tile ----------------
__global__ __launch_bounds__(256) void gemm_out(const short* __restrict__ A,
                                                const short* __restrict__ Bt,
                                                const float* __restrict__ bias,
                                                float* __restrict__ C,
                                                int M, int N, int K) {
  __shared__ __attribute__((aligned(16))) short aT0[64 * 32];
  __shared__ __attribute__((aligned(16))) short aT1[64 * 32];
  __shared__ __attribute__((aligned(16))) short bT0[128 * 32];
  __shared__ __attribute__((aligned(16))) short bT1[128 * 32];
  int tid = threadIdx.x;
  int wave = tid >> 6, lane = tid & 63;
  int lhi = lane >> 4, llo = lane & 15;
  int wr = wave >> 1, wc = wave & 1;
  int m0 = blockIdx.y * 64, n0 = blockIdx.x * 128;
  int lr = lane >> 2, lc = (lane & 3) * 8;

  f32x4 acc[2][4];
#pragma unroll
  for (int a = 0; a < 2; a++)
#pragma unroll
    for (int b = 0; b < 4; b++) acc[a][b] = (f32x4){0.f, 0.f, 0.f, 0.f};

  const short* Ab = A + (long)m0 * K;
  const short* Bb = Bt + (long)n0 * K;

#define COMPUTE_KS(AT, BT)                                                   \
  {                                                                          \
    short8 af[2], bf[4];                                                     \
    _Pragma("unroll") for (int mi = 0; mi < 2; mi++)                         \
        af[mi] = *(const short8*)&AT[(wr * 32 + mi * 16 + llo) * 32 + lhi * 8]; \
    _Pragma("unroll") for (int ni = 0; ni < 4; ni++)                         \
        bf[ni] = *(const short8*)&BT[(wc * 64 + ni * 16 + llo) * 32 + lhi * 8]; \
    _Pragma("unroll") for (int mi = 0; mi < 2; mi++)                         \
        _Pragma("unroll") for (int ni = 0; ni < 4; ni++)                     \
            acc[mi][ni] = mfma16(af[mi], bf[ni], acc[mi][ni]);               \
  }

  for (int k0 = 0; k0 < K; k0 += 64) {
    {
      long aoff = (long)(wave * 16 + lr) * K + k0 + lc;
      gload16(Ab + aoff, &aT0[wave * 512]);
      gload16(Ab + aoff + 32, &aT1[wave * 512]);
    }
#pragma unroll
    for (int it = 0; it < 2; it++) {
      int c = wave * 2 + it;
      long boff = (long)(c * 16 + lr) * K + k0 + lc;
      gload16(Bb + boff, &bT0[c * 512]);
      gload16(Bb + boff + 32, &bT1[c * 512]);
    }
    __syncthreads();
    COMPUTE_KS(aT0, bT0);
    COMPUTE_KS(aT1, bT1);
    __syncthreads();
  }
#undef COMPUTE_KS

#pragma unroll
  for (int mi = 0; mi < 2; mi++)
#pragma unroll
    for (int ni = 0; ni < 4; ni++)
#pragma unroll
      for (int r = 0; r < 4; r++) {
        int row = m0 + wr * 32 + mi * 16 + lhi * 4 + r;
        int col = n0 + wc * 64 + ni * 16 + llo;
        C[row * (long)N + col] = acc[mi][ni][r] + bias[col];
      }
}

// ---------------- Flash attention, split-K (chunks of <=8 KV-tiles) ----------------
__global__ __launch_bounds__(256) void attn_kernel(const short* __restrict__ Qb,
                                                   const short* __restrict__ Kb,
                                                   const short* __restrict__ Vt,
                                                   short* __restrict__ Opart,
                                                   float* __restrict__ ml) {
  __shared__ __attribute__((aligned(16))) short Kl[2][64 * 136];
  __shared__ __attribute__((aligned(16))) short Vl[2][128 * 72];
  __shared__ __attribute__((aligned(16))) short Pl[4][16 * 72];
  int bid = blockIdx.x;
  int x = bid & 7, j = bid >> 3;
  int h = (x << 1) | (j >= 80 ? 1 : 0);
  int c = (j >= 80 ? j - 80 : j);
  c = 79 - c;
  int qt = 0;
  for (; qt < 32; qt++) {
    int nc = (qt >> 3) + 1;
    if (c < nc) break;
    c -= nc;
  }
  int ci = c;
  int kt0 = ci * 8;
  int kt1 = min(qt + 1, kt0 + 8);
  int slot = ((h * 32 + qt) << 2) + ci;

  int tid = threadIdx.x;
  int wave = tid >> 6, lane = tid & 63;
  int lhi = lane >> 4, llo = lane & 15;
  int qrow0 = qt * 64 + wave * 16;

  const short* Kh = Kb + (long)h * SEQ * HD;
  const short* Vh = Vt + (long)h * HD * SEQ;

  short8 qf[4];
  const short* Qbase = Qb + (long)(h * SEQ + qrow0 + llo) * HD;
#pragma unroll
  for (int sl = 0; sl < 4; sl++) qf[sl] = *(const short8*)(Qbase + sl * 32 + lhi * 8);

  f32x4 oacc[8];
#pragma unroll
  for (int cb = 0; cb < 8; cb++) oacc[cb] = (f32x4){0.f, 0.f, 0.f, 0.f};
  float m[4], l[4];
#pragma unroll
  for (int r = 0; r < 4; r++) { m[r] = -INFINITY; l[r] = 0.f; }

  short8 kreg[4], vreg[4];
#define ISSUE_KV(T)                                                                     \
  {                                                                                     \
    _Pragma("unroll") for (int i = 0; i < 4; i++) {                                     \
      int s = tid + i * 256;                                                            \
      kreg[i] = *(const short8*)(Kh + (long)((T) * 64 + (s >> 4)) * HD + (s & 15) * 8); \
      vreg[i] = *(const short8*)(Vh + (long)(s >> 3) * SEQ + (T) * 64 + (s & 7) * 8);   \
    }                                                                                   \
  }
#define WRITE_KV(BUF)                                                        \
  {                                                                          \
    _Pragma("unroll") for (int i = 0; i < 4; i++) {                          \
      int s = tid + i * 256;                                                 \
      *(short8*)&Kl[BUF][(s >> 4) * 136 + (s & 15) * 8] = kreg[i];           \
      *(short8*)&Vl[BUF][(s >> 3) * 72 + (s & 7) * 8] = vreg[i];             \
    }                                                                        \
  }

  ISSUE_KV(kt0);
  WRITE_KV(0);
  __syncthreads();

  int cur = 0;
  for (int t = kt0; t < kt1; t++) {
    bool pre = (t + 1 < kt1);
    if (pre) ISSUE_KV(t + 1);

    f32x4 sfr[4];
#pragma unroll
    for (int kb = 0; kb < 4; kb++) {
      sfr[kb] = (f32x4){0.f, 0.f, 0.f, 0.f};
#pragma unroll
      for (int sl = 0; sl < 4; sl++) {
        short8 bk = *(const short8*)&Kl[cur][(kb * 16 + llo) * 136 + sl * 32 + lhi * 8];
        sfr[kb] = mfma16(qf[sl], bk, sfr[kb]);
      }
    }

    if (t == qt) {
#pragma unroll
      for (int kb = 0; kb < 4; kb++)
#pragma unroll
        for (int r = 0; r < 4; r++) {
          int kg = t * 64 + kb * 16 + llo;
          int qg = qrow0 + lhi * 4 + r;
          if (kg > qg) sfr[kb][r] = -1e30f;
        }
    }

    float tmax[4];
#pragma unroll
    for (int r = 0; r < 4; r++)
      tmax[r] = fmaxf(fmaxf(sfr[0][r], sfr[1][r]), fmaxf(sfr[2][r], sfr[3][r]));
#pragma unroll
    for (int r = 0; r < 4; r++)
#pragma unroll
      for (int msk = 1; msk < 16; msk <<= 1)
        tmax[r] = fmaxf(tmax[r], __shfl_xor(tmax[r], msk));

    float grow = fmaxf(fmaxf(tmax[0] - m[0], tmax[1] - m[1]),
                       fmaxf(tmax[2] - m[2], tmax[3] - m[3]));
    if (!__all(grow <= 8.0f)) {
#pragma unroll
      for (int r = 0; r < 4; r++) {
        float mn = fmaxf(m[r], tmax[r]);
        float alpha = __expf(m[r] - mn);
        m[r] = mn;
        l[r] *= alpha;
#pragma unroll
        for (int cb = 0; cb < 8; cb++) oacc[cb][r] *= alpha;
      }
    }

    float psum[4];
#pragma unroll
    for (int r = 0; r < 4; r++) psum[r] = 0.f;
#pragma unroll
    for (int kb = 0; kb < 4; kb++)
#pragma unroll
      for (int r = 0; r < 4; r++) {
        float p = __expf(sfr[kb][r] - m[r]);
        psum[r] += p;
        Pl[wave][(lhi * 4 + r) * 72 + kb * 16 + llo] = f2b(p);
      }
#pragma unroll
    for (int r = 0; r < 4; r++) {
#pragma unroll
      for (int msk = 1; msk < 16; msk <<= 1) psum[r] += __shfl_xor(psum[r], msk);
      l[r] += psum[r];
    }

#pragma unroll
    for (int ks = 0; ks < 2; ks++) {
      short8 pa = *(const short8*)&Pl[wave][llo * 72 + ks * 32 + lhi * 8];
#pragma unroll
      for (int cb = 0; cb < 8; cb++) {
        short8 bv = *(const short8*)&Vl[cur][(cb * 16 + llo) * 72 + ks * 32 + lhi * 8];
        oacc[cb] = mfma16(pa, bv, oacc[cb]);
      }
    }

    if (pre) {
      WRITE_KV(cur ^ 1);
      __syncthreads();
      cur ^= 1;
    }
  }
#undef ISSUE_KV
#undef WRITE_KV

  long obase = (long)slot * (64 * 128);
#pragma unroll
  for (int cb = 0; cb < 8; cb++)
#pragma unroll
    for (int r = 0; r < 4; r++) {
      int row = wave * 16 + lhi * 4 + r;
      Opart[obase + row * 128 + cb * 16 + llo] = f2b(oacc[cb][r]);
    }
  if (llo == 0) {
#pragma unroll
    for (int r = 0; r < 4; r++) {
      int row = wave * 16 + lhi * 4 + r;
      ml[slot * 128 + row * 2 + 0] = m[r];
      ml[slot * 128 + row * 2 + 1] = l[r];
    }
  }
}

// ---------------- merge split-K partials -> attn bf16 [s][h*128+d] ----------------
__global__ __launch_bounds__(256) void attn_merge(const short* __restrict__ Opart,
                                                  const float* __restrict__ ml,
                                                  short* __restrict__ out) {
  int qt = blockIdx.x, h = blockIdx.y;
  int nc = (qt >> 3) + 1;
  int tid = threadIdx.x;
  int row = tid >> 2;
  int c0 = (tid & 3) * 32;
  int slot0 = (h * 32 + qt) << 2;

  float mm[4], ll[4], alpha[4];
  float M = -INFINITY;
  for (int i = 0; i < nc; i++) {
    mm[i] = ml[(slot0 + i) * 128 + row * 2 + 0];
    ll[i] = ml[(slot0 + i) * 128 + row * 2 + 1];
    M = fmaxf(M, mm[i]);
  }
  float L = 0.f;
  for (int i = 0; i < nc; i++) {
    alpha[i] = __expf(mm[i] - M);
    L += ll[i] * alpha[i];
  }
  float invL = 1.0f / L;

  int s = qt * 64 + row;
#pragma unroll
  for (int cc = 0; cc < 32; cc += 8) {
    float acc[8];
#pragma unroll
    for (int jj = 0; jj < 8; jj++) acc[jj] = 0.f;
    for (int i = 0; i < nc; i++) {
      short8 v = *(const short8*)&Opart[(long)(slot0 + i) * 8192 + row * 128 + c0 + cc];
#pragma unroll
      for (int jj = 0; jj < 8; jj++) acc[jj] += alpha[i] * b2f(v[jj]);
    }
    short8 o;
#pragma unroll
    for (int jj = 0; jj < 8; jj++) o[jj] = f2b(acc[jj] * invL);
    *(short8*)&out[s * HID + h * HD + c0 + cc] = o;
  }
}

extern "C" void kernel_launch(void* const* d_in, const int* in_sizes, int n_in,
                              void* d_out, int out_size, void* d_ws, size_t ws_size,
                              hipStream_t stream) {
  (void)in_sizes; (void)n_in; (void)out_size; (void)ws_size;
  const float* hs = (const float*)d_in[0];
  // d_in[1] = attention_mask (tril causal) — enforced structurally
  const float* w1 = (const float*)d_in[2];
  const float* b1 = (const float*)d_in[3];
  const float* w2 = (const float*)d_in[4];
  const float* b2 = (const float*)d_in[5];
  float* out = (float*)d_out;
  char* ws = (char*)d_ws;

  // Opart (32MB) overlays hsb+w1t — both dead after the QKV GEMM (stream-ordered).
  short* hsb   = (short*)(ws);                 // [0,8) MB
  short* w1t   = (short*)(ws + (8L << 20));    // [8,32) MB
  short* Opart = (short*)(ws);                 // [0,32) MB (after QKV GEMM)
  short* w2t   = (short*)(ws + (32L << 20));   // [32,40) MB
  short* qkvb  = (short*)(ws + (40L << 20));   // [40,64) MB
  short* Qb    = (short*)(ws + (64L << 20));   // [64,72) MB
  short* Kb    = (short*)(ws + (72L << 20));   // [72,80) MB
  short* Vt    = (short*)(ws + (80L << 20));   // [80,88) MB
  short* attnb = (short*)(ws + (88L << 20));   // [88,96) MB
  float* ml    = (float*)(ws + (96L << 20));   // [96,97) MB

  cast_f32_bf16<<<(SEQ * HID) / 2048, 256, 0, stream>>>(hs, hsb, SEQ * HID);
  tr_cast<<<dim3(N1 / 32, HID / 32), dim3(32, 8), 0, stream>>>(w1, w1t, HID, N1);
  tr_cast<<<dim3(HID / 32, HID / 32), dim3(32, 8), 0, stream>>>(w2, w2t, HID, HID);
  gemm_bt<1><<<dim3(N1 / 128, SEQ / 128), 256, 0, stream>>>(hsb, w1t, b1, qkvb, SEQ, N1, HID);
  rope_v<<<dim3(HD / 32, SEQ / 32, NH), dim3(32, 8), 0, stream>>>(qkvb, Qb, Kb, Vt);
  attn_kernel<<<1280, 256, 0, stream>>>(Qb, Kb, Vt, Opart, ml);
  attn_merge<<<dim3(32, 16), 256, 0, stream>>>(Opart, ml, attnb);
  gemm_out<<<dim3(HID / 128, SEQ / 64), 256, 0, stream>>>(attnb, w2t, b2, out, SEQ, HID, HID);
}